// Round 1
// baseline (574.854 us; speedup 1.0000x reference)
//
#include <hip/hip_runtime.h>

#define IN_C   16
#define OUT_C  16
#define COEF_M 11
#define PLANE  16384   // 128*128
#define WSIZE  3328    // IN_C*OUT_C*COEF_M + 2*IN_C*OUT_C
#define I0     2816    // IN_C*OUT_C*COEF_M
#define I1     3072    // I0 + IN_C*OUT_C

// v2: latency-hiding restructure.
//   thread = 1 input channel x 2 pixels (float2 global loads, 512 B/wave-instr)
//   block  = 256 threads = 16 px-pairs (32 px) x 16 i-channels
//   grid   = 32768 px / 32 = 1024 blocks -> 4 blocks/CU, 16 waves/CU
// __launch_bounds__(256,4): 4 waves/EU min -> VGPR cap 128 so 4 blocks/CU stick.
__global__ __launch_bounds__(256, 4) void kan_kernel(
    const float* __restrict__ x, const float* __restrict__ w,
    float* __restrict__ out)
{
    const int tid = threadIdx.x;
    const int pp  = tid & 15;        // pixel-pair index within block
    const int i   = tid >> 4;        // input channel owned by this thread
    const int pixel0 = blockIdx.x * 32 + pp * 2;
    const int b  = pixel0 >> 14;     // PLANE = 2^14; blocks never straddle b
    const int hw = pixel0 & (PLANE - 1);

    const float* wb = w + (size_t)b * WSIZE * PLANE + hw;
    const float* xb = x + (size_t)b * IN_C * PLANE + hw;

    // x for 2 pixels of channel i
    const float2 x2 = *(const float2*)(xb + (size_t)i * PLANE);

    // Cox-de Boor, order K=3, uniform knots t_j = -1.75 + 0.25*j, for both pixels
    float bpa[14], bpb[14];
    #pragma unroll
    for (int j = 0; j < 14; ++j) {
        const float tj  = -1.75f + 0.25f * j;
        const float tj1 = tj + 0.25f;
        bpa[j] = (x2.x >= tj && x2.x < tj1) ? 1.0f : 0.0f;
        bpb[j] = (x2.y >= tj && x2.y < tj1) ? 1.0f : 0.0f;
    }
    #pragma unroll
    for (int p = 1; p <= 3; ++p) {
        const float inv = 1.0f / (0.25f * (float)p);
        #pragma unroll
        for (int j = 0; j < 14 - p; ++j) {
            const float tj  = -1.75f + 0.25f * j;
            const float tp1 = tj + 0.25f * (float)(p + 1);
            const float la = (x2.x - tj) * inv;
            const float ra = (tp1 - x2.x) * inv;
            bpa[j] = la * bpa[j] + ra * bpa[j + 1];
            const float lb = (x2.y - tj) * inv;
            const float rb = (tp1 - x2.y) * inv;
            bpb[j] = lb * bpb[j] + rb * bpb[j + 1];
        }
    }

    const float sxa = x2.x / (1.0f + __expf(-x2.x));   // silu
    const float sxb = x2.y / (1.0f + __expf(-x2.y));

    const float* ci = wb + (size_t)(i * (OUT_C * COEF_M)) * PLANE;
    const float* ui = wb + (size_t)(I0 + i * OUT_C) * PLANE;
    const float* ri = wb + (size_t)(I1 + i * OUT_C) * PLANE;

    float acca[OUT_C], accb[OUT_C];
    #pragma unroll
    for (int o = 0; o < OUT_C; ++o) {
        const float* c = ci + (size_t)(o * COEF_M) * PLANE;
        float spa = 0.0f, spb = 0.0f;
        #pragma unroll
        for (int m = 0; m < COEF_M; ++m) {
            const float2 cv = *(const float2*)(c + (size_t)m * PLANE);
            spa += cv.x * bpa[m];
            spb += cv.y * bpb[m];
        }
        const float2 uv = *(const float2*)(ui + (size_t)o * PLANE);
        const float2 rv = *(const float2*)(ri + (size_t)o * PLANE);
        acca[o] = uv.x * spa + rv.x * sxa;
        accb[o] = uv.y * spb + rv.y * sxb;
    }

    // reduce partials across the 16 i-channels via LDS
    // row stride 33 words -> banks (16*i + pp + ...) mod 32: <=2-way aliasing on writes
    __shared__ float red[16 * 16 * 33];
    const int row = (i * 16 + pp) * 33;
    #pragma unroll
    for (int o = 0; o < OUT_C; ++o) {
        red[row + 2 * o]     = acca[o];
        red[row + 2 * o + 1] = accb[o];
    }
    __syncthreads();

    // store phase: 32 px x 16 o per block = 512 outputs; 2 per thread
    const int px = tid & 31;                 // consecutive lanes -> consecutive hw
    const int og = tid >> 5;                 // 8 o-groups of 2
    const int rp = (px >> 1) * 33 + (px & 1);
    const int pixel = blockIdx.x * 32 + px;
    const int ob = pixel >> 14;
    const int ohw = pixel & (PLANE - 1);
    #pragma unroll
    for (int k = 0; k < 2; ++k) {
        const int o = og * 2 + k;
        float s = 0.0f;
        #pragma unroll
        for (int g2 = 0; g2 < 16; ++g2)
            s += red[g2 * (16 * 33) + rp + 2 * o];
        out[(size_t)ob * (OUT_C * PLANE) + (size_t)o * PLANE + ohw] = s;
    }
}

extern "C" void kernel_launch(void* const* d_in, const int* in_sizes, int n_in,
                              void* d_out, int out_size, void* d_ws, size_t ws_size,
                              hipStream_t stream) {
    const float* x = (const float*)d_in[0];   // (2,16,128,128) fp32
    const float* w = (const float*)d_in[1];   // (2,3328,128,128) fp32
    float* out = (float*)d_out;               // (2,16,128,128) fp32

    kan_kernel<<<dim3(1024), dim3(256), 0, stream>>>(x, w, out);
}